// Round 8
// baseline (488.689 us; speedup 1.0000x reference)
//
#include <hip/hip_runtime.h>
#include <math.h>

// Problem constants (from reference)
#define NNODES 100000
#define NREL 500
#define E1 288000
#define ETOT 320000
#define LALPHA 0.2f
#define SEPS 1e-16f
#define NB_SCAN ((NNODES + 255) / 256)  // 391 blocks of 256 for the scan
#define GTILES 6250                      // 100000 / 16 row-tiles, exact
#define GTPB 5                           // tiles per block
#define GGRID (GTILES / GTPB)            // 1250 blocks, exact

typedef __attribute__((ext_vector_type(8))) short bf16x8;
typedef __attribute__((ext_vector_type(4))) float f32x4;

// fp32 -> bf16 (round-to-nearest-even), header-independent
__device__ __forceinline__ unsigned short f2bf(float x) {
  unsigned int u = __float_as_uint(x);
  unsigned int r = (u + 0x7fffu + ((u >> 16) & 1u)) >> 16;
  return (unsigned short)r;
}
// pack two fp32 as bf16 pair (lo, hi) in one uint
__device__ __forceinline__ unsigned int packbf2(float lo, float hi) {
  return (unsigned int)f2bf(lo) | ((unsigned int)f2bf(hi) << 16);
}
__device__ __forceinline__ float unpk_lo(unsigned int u) { return __uint_as_float(u << 16); }
__device__ __forceinline__ float unpk_hi(unsigned int u) {
  return __uint_as_float(u & 0xffff0000u);
}
__device__ __forceinline__ float lrelu(float e) { return (e >= 0.f) ? e : LALPHA * e; }

// 8 fp32 (two uint4 bit-views) -> 8 bf16 packed in uint4
__device__ __forceinline__ uint4 cvt8(uint4 u0, uint4 u1) {
  uint4 o;
  o.x = packbf2(__uint_as_float(u0.x), __uint_as_float(u0.y));
  o.y = packbf2(__uint_as_float(u0.z), __uint_as_float(u0.w));
  o.z = packbf2(__uint_as_float(u1.x), __uint_as_float(u1.y));
  o.w = packbf2(__uint_as_float(u1.z), __uint_as_float(u1.w));
  return o;
}

// ---------------- wave (64-lane) reductions ----------------
__device__ __forceinline__ float wave_max64(float v) {
#pragma unroll
  for (int o = 32; o >= 1; o >>= 1) v = fmaxf(v, __shfl_xor(v, o, 64));
  return v;
}
__device__ __forceinline__ float wave_sum64(float v) {
#pragma unroll
  for (int o = 32; o >= 1; o >>= 1) v += __shfl_xor(v, o, 64);
  return v;
}
// reduce across the 16 lanes of a colv-group (bits 0..3)
__device__ __forceinline__ float red16(float v) {
  v += __shfl_xor(v, 1, 64);
  v += __shfl_xor(v, 2, 64);
  v += __shfl_xor(v, 4, 64);
  v += __shfl_xor(v, 8, 64);
  return v;
}

// ---------------- CSR build ----------------
__global__ void k_zero_int(int* __restrict__ p, int n) {
  int i = blockIdx.x * blockDim.x + threadIdx.x;
  if (i < n) p[i] = 0;
}

__global__ void k_count(const int* __restrict__ src, int* __restrict__ cnt) {
  int e = blockIdx.x * blockDim.x + threadIdx.x;
  if (e < ETOT) atomicAdd(&cnt[src[e]], 1);
}

__global__ void k_scan_a(const int* __restrict__ cnt, int* __restrict__ rowstart,
                         int* __restrict__ blockTot) {
  __shared__ int s[256];
  int t = threadIdx.x;
  int idx = blockIdx.x * 256 + t;
  int v = (idx < NNODES) ? cnt[idx] : 0;
  s[t] = v;
  __syncthreads();
  for (int off = 1; off < 256; off <<= 1) {
    int xv = (t >= off) ? s[t - off] : 0;
    __syncthreads();
    s[t] += xv;
    __syncthreads();
  }
  if (idx < NNODES) rowstart[idx] = s[t] - v;  // exclusive within block
  if (t == 255) blockTot[blockIdx.x] = s[255];
}

__global__ void k_scan_b(const int* __restrict__ blockTot, int* __restrict__ blockOff) {
  __shared__ int s[512];
  int t = threadIdx.x;
  int v = (t < NB_SCAN) ? blockTot[t] : 0;
  s[t] = v;
  __syncthreads();
  for (int off = 1; off < 512; off <<= 1) {
    int xv = (t >= off) ? s[t - off] : 0;
    __syncthreads();
    s[t] += xv;
    __syncthreads();
  }
  if (t < NB_SCAN) blockOff[t] = s[t] - v;  // exclusive
}

__global__ void k_scan_c(int* __restrict__ rowstart, const int* __restrict__ blockOff,
                         int* __restrict__ cursor) {
  int idx = blockIdx.x * 256 + threadIdx.x;
  if (idx < NNODES) {
    int v = rowstart[idx] + blockOff[blockIdx.x];
    rowstart[idx] = v;
    cursor[idx] = v;
  }
  if (idx == 0) rowstart[NNODES] = ETOT;
}

__global__ void k_scatter(const int* __restrict__ src, int* __restrict__ cursor,
                          int* __restrict__ perm) {
  int e = blockIdx.x * blockDim.x + threadIdx.x;
  if (e < ETOT) {
    int pos = atomicAdd(&cursor[src[e]], 1);
    perm[pos] = e;
  }
}

// ---------------- relation-level precompute ----------------
// rW1p[t][l] = bf16pair(rW1[t][h0][l], rW1[t][h1][l]); srel1[t][h] = rW1[t][h] . a_heads[h]
__global__ void k_relprep1(const float* __restrict__ r, const float* __restrict__ Wh,
                           const float* __restrict__ ah, unsigned int* __restrict__ rW1p,
                           float* __restrict__ srel1) {
  __shared__ float vals[128];
  int t = blockIdx.x;    // 0..499
  int tid = threadIdx.x; // 0..127: h = tid>>6, kk = tid&63
  int h = tid >> 6, kk = tid & 63;
  const float* wcol = Wh + h * 24576 + 256 * 64 + kk;
  const float* rrow = r + t * 128;
  float acc = 0.f;
#pragma unroll 4
  for (int d = 0; d < 128; ++d) acc = fmaf(rrow[d], wcol[d * 64], acc);
  vals[tid] = acc;
  float p = wave_sum64(acc * ah[h * 64 + kk]);
  if (kk == 0) srel1[t * 2 + h] = p;
  __syncthreads();
  if (tid < 64) rW1p[t * 64 + tid] = packbf2(vals[tid], vals[64 + tid]);
}

// r2[t][c] = sum_d r[t][d] * W_r[d][c]   (also one of the two outputs)
__global__ void k_r2(const float* __restrict__ r, const float* __restrict__ Wr,
                     float* __restrict__ r2out) {
  int t = blockIdx.x;   // 0..499
  int c = threadIdx.x;  // 0..127
  float acc = 0.f;
#pragma unroll 4
  for (int d = 0; d < 128; ++d) acc = fmaf(r[t * 128 + d], Wr[d * 128 + c], acc);
  r2out[t * 128 + c] = acc;
}

// rW2p[t][l] = bf16pair(rW2[t][l], rW2[t][64+l]); srel2[t] = rW2[t] . a_out
__global__ void k_relprep2(const float* __restrict__ r2, const float* __restrict__ Wo,
                           const float* __restrict__ ao, unsigned int* __restrict__ rW2p,
                           float* __restrict__ srel2) {
  __shared__ float s[128];
  __shared__ float vals[128];
  int t = blockIdx.x;   // 0..499
  int k = threadIdx.x;  // 0..127
  float acc = 0.f;
#pragma unroll 4
  for (int d = 0; d < 128; ++d) acc = fmaf(r2[t * 128 + d], Wo[(256 + d) * 128 + k], acc);
  vals[k] = acc;
  s[k] = acc * ao[k];
  __syncthreads();
  for (int off = 64; off >= 1; off >>= 1) {
    if (k < off) s[k] += s[k + off];
    __syncthreads();
  }
  if (k == 0) srel2[t] = s[0];
  if (k < 64) rW2p[t * 64 + k] = packbf2(vals[k], vals[64 + k]);
}

// ---------------- MFMA weight packing: Wb[c][d] bf16, B^T layout ----------------
template <int LAYER>
__global__ void k_packb(const float* __restrict__ W, unsigned short* __restrict__ Wb) {
  int c = blockIdx.x;   // 0..255
  int d = threadIdx.x;  // 0..127
  float v;
  if (LAYER == 1) {
    int h = (c >> 6) & 1, part = c >> 7, kc = c & 63;
    v = W[h * 24576 + (part * 128 + d) * 64 + kc];
  } else {
    int part = c >> 7, kc = c & 127;
    v = W[(part * 128 + d) * 128 + kc];
  }
  Wb[c * 128 + d] = f2bf(v);
}

// ---------------- MFMA GEMM: xWp[N][128] (bf16-pair) = X[N][128] @ Wb^T ----------------
// W held in registers (loaded once/wave): wave owns col-tiles {w, w+4, w+8, w+12} so that
// bf16-pair partners (c, c+64) stay in-wave. A staged via LDS (4 KB tile, XOR-swizzled
// chunks -> conflict-free ds_read_b128), reg-staged prefetch of the next tile overlaps MFMA.
// sc accumulated via fp32 global atomics (sc must be zeroed before launch).
template <int LAYER>
__global__ __launch_bounds__(256) void k_gemm_mfma(const void* __restrict__ Xin,
                                                   const unsigned short* __restrict__ Wb,
                                                   const float* __restrict__ avec,
                                                   unsigned int* __restrict__ xWp,
                                                   float* __restrict__ sc) {
  __shared__ unsigned int lds[1024];  // 16 rows x 64 dwords (bf16), swizzled
  const int tid = threadIdx.x;
  const int lane = tid & 63;
  const int wave = tid >> 6;  // w = owned col-group
  const int colv = lane & 15;
  const int kg = lane >> 4;
  const int srow = tid >> 4, sch = tid & 15;
  const int swz = sch ^ (srow & 7);  // staging chunk swizzle (16-B chunks)

  // ---- W fragments: 16 x b128, loaded once (Wb is 64 KB, L2-resident) ----
  bf16x8 b[4][4];
#pragma unroll
  for (int j = 0; j < 4; ++j) {
#pragma unroll
    for (int s = 0; s < 4; ++s)
      b[j][s] =
          *(const bf16x8*)(Wb + (size_t)((wave + 4 * j) * 16 + colv) * 128 + s * 32 + kg * 8);
  }
  const float av0 = avec[wave * 16 + colv];       // tiles w, w+8   (c&127 < 64)
  const float av1 = avec[64 + wave * 16 + colv];  // tiles w+4, w+12

  const uint4* xg = (const uint4*)Xin;
  int tile = blockIdx.x * GTPB;

  // ---- prologue: stage tile 0 ----
  if (LAYER == 1) {
    uint4 u0 = xg[(size_t)tile * 512 + tid * 2];
    uint4 u1 = xg[(size_t)tile * 512 + tid * 2 + 1];
    *(uint4*)&lds[srow * 64 + swz * 4] = cvt8(u0, u1);
  } else {
    *(uint4*)&lds[srow * 64 + swz * 4] = xg[(size_t)tile * 256 + tid];
  }
  __syncthreads();

  for (int it = 0; it < GTPB; ++it, ++tile) {
    // issue next tile's global loads (latency hides under ds_read+MFMA+stores)
    uint4 n0, n1;
    const bool hasnext = (it + 1 < GTPB);
    if (hasnext) {
      if (LAYER == 1) {
        n0 = xg[(size_t)(tile + 1) * 512 + tid * 2];
        n1 = xg[(size_t)(tile + 1) * 512 + tid * 2 + 1];
      } else {
        n0 = xg[(size_t)(tile + 1) * 256 + tid];
      }
    }

    // A fragments from LDS (swizzled; 2-way bank alias = free)
    bf16x8 a[4];
#pragma unroll
    for (int s = 0; s < 4; ++s)
      a[s] = *(const bf16x8*)&lds[colv * 64 + (((s * 4 + kg) ^ (colv & 7)) << 2)];

    f32x4 acc[4];
#pragma unroll
    for (int j = 0; j < 4; ++j) acc[j] = (f32x4){0.f, 0.f, 0.f, 0.f};
#pragma unroll
    for (int s = 0; s < 4; ++s)
#pragma unroll
      for (int j = 0; j < 4; ++j)
        acc[j] = __builtin_amdgcn_mfma_f32_16x16x32_bf16(a[s], b[j][s], acc[j], 0, 0, 0);

    // ---- epilogue: packed stores + sc atomics ----
    const int rbase = tile * 16 + kg * 4;
#pragma unroll
    for (int i = 0; i < 4; ++i) {
      unsigned int* orow = xWp + (size_t)(rbase + i) * 128;
      orow[wave * 16 + colv] = packbf2(acc[0][i], acc[1][i]);
      orow[64 + wave * 16 + colv] = packbf2(acc[2][i], acc[3][i]);
      if (LAYER == 1) {
        float p0 = red16(acc[0][i] * av0);  // slot 0: h0,part0 (tile w)
        float p2 = red16(acc[1][i] * av1);  // slot 2: h1,part0 (tile w+4)
        float p1 = red16(acc[2][i] * av0);  // slot 1: h0,part1 (tile w+8)
        float p3 = red16(acc[3][i] * av1);  // slot 3: h1,part1 (tile w+12)
        if (colv == 0) {
          float* sp = sc + (size_t)(rbase + i) * 4;
          atomicAdd(sp + 0, p0);
          atomicAdd(sp + 1, p1);
          atomicAdd(sp + 2, p2);
          atomicAdd(sp + 3, p3);
        }
      } else {
        float p0 = red16(fmaf(acc[1][i], av1, acc[0][i] * av0));  // part0
        float p1 = red16(fmaf(acc[3][i], av1, acc[2][i] * av0));  // part1
        if (colv == 0) {
          float* sp = sc + (size_t)(rbase + i) * 2;
          atomicAdd(sp + 0, p0);
          atomicAdd(sp + 1, p1);
        }
      }
    }

    __syncthreads();  // everyone done reading LDS
    if (hasnext) {
      if (LAYER == 1)
        *(uint4*)&lds[srow * 64 + swz * 4] = cvt8(n0, n1);
      else
        *(uint4*)&lds[srow * 64 + swz * 4] = n0;
    }
    __syncthreads();  // LDS ready for next iteration
  }
}

// ---------------- edge-parallel logit precompute ----------------
__global__ void k_eprep1(const int* __restrict__ perm, const int* __restrict__ srcA,
                         const int* __restrict__ dstA, const int* __restrict__ et,
                         const int* __restrict__ et2, const float* __restrict__ sc1,
                         const float* __restrict__ srel1, int* __restrict__ srcp,
                         int* __restrict__ dnp, int2* __restrict__ t12,
                         float2* __restrict__ lgp1) {
  int p = blockIdx.x * 256 + threadIdx.x;
  if (p >= ETOT) return;
  int ed = perm[p];
  int src = srcA[ed], dn = dstA[ed];
  int t1, t2 = -1;
  float rel0, rel1;
  if (ed < E1) {
    t1 = et[ed];
    float2 sr = ((const float2*)srel1)[t1];
    rel0 = sr.x;
    rel1 = sr.y;
  } else {
    int2 tt = ((const int2*)et2)[ed - E1];
    t1 = tt.x;
    t2 = tt.y;
    float2 sa = ((const float2*)srel1)[t1];
    float2 sb = ((const float2*)srel1)[t2];
    rel0 = sa.x + sb.x;
    rel1 = sa.y + sb.y;
  }
  float4 ssv = ((const float4*)sc1)[src];
  float4 sdv = ((const float4*)sc1)[dn];
  lgp1[p] = make_float2(lrelu(ssv.x + sdv.y + rel0), lrelu(ssv.z + sdv.w + rel1));
  srcp[p] = src;
  dnp[p] = dn;
  t12[p] = make_int2(t1, t2);
}

__global__ void k_eprep2(const int* __restrict__ srcp, const int* __restrict__ dnp,
                         const int2* __restrict__ t12, const float* __restrict__ sc2,
                         const float* __restrict__ srel2, float* __restrict__ lgp2) {
  int p = blockIdx.x * 256 + threadIdx.x;
  if (p >= ETOT) return;
  int src = srcp[p], dn = dnp[p];
  int2 tt = t12[p];
  float rel = srel2[tt.x];
  if (tt.y >= 0) rel += srel2[tt.y];
  float2 ssv = ((const float2*)sc2)[src];
  float2 sdv = ((const float2*)sc2)[dn];
  lgp2[p] = lrelu(ssv.x + sdv.y + rel);
}

// ---------------- layer-1 aggregation: wave/node, 4-edge-parallel groups ----------------
__global__ __launch_bounds__(256) void k_agg1(
    const int* __restrict__ rowstart, const float2* __restrict__ lgp1,
    const int* __restrict__ dnp, const int2* __restrict__ t12,
    const unsigned int* __restrict__ xWp, const unsigned int* __restrict__ rW1p,
    unsigned short* __restrict__ x1b) {
  int n = blockIdx.x * 4 + (threadIdx.x >> 6);
  int lane = threadIdx.x & 63;
  int q = lane & 15, g = lane >> 4;
  int s0 = rowstart[n];
  int deg = rowstart[n + 1] - s0;
  int jj = q + 16 * g;
  float r0 = 0.f, r1 = 0.f;
  if (deg > 0) {
    float m0 = -3.4e38f, m1 = -3.4e38f, d0 = 0.f, d1 = 0.f;
    float ac0[4] = {0.f, 0.f, 0.f, 0.f}, ac1[4] = {0.f, 0.f, 0.f, 0.f};
    for (int base = 0; base < deg; base += 64) {
      int i = base + lane;
      float lg0 = -3.4e38f, lg1 = -3.4e38f;
      int dn = 0;
      int2 tt = make_int2(0, -1);
      if (i < deg) {
        float2 l2 = lgp1[s0 + i];
        lg0 = l2.x;
        lg1 = l2.y;
        dn = dnp[s0 + i];
        tt = t12[s0 + i];
      }
      float nm0 = fmaxf(m0, wave_max64(lg0));
      float nm1 = fmaxf(m1, wave_max64(lg1));
      float rs0 = __expf(m0 - nm0), rs1 = __expf(m1 - nm1);
      float w0 = __expf(lg0 - nm0), w1 = __expf(lg1 - nm1);  // invalid lanes -> 0
      d0 = d0 * rs0 + wave_sum64(w0);
      d1 = d1 * rs1 + wave_sum64(w1);
#pragma unroll
      for (int k = 0; k < 4; ++k) {
        ac0[k] *= rs0;
        ac1[k] *= rs1;
      }
      m0 = nm0;
      m1 = nm1;
      int cnt = min(64, deg - base);
      int steps = (cnt + 3) >> 2;
      for (int s = 0; s < steps; ++s) {
        int e = s * 4 + g;  // this group's edge within the chunk (<=63)
        float a0 = __shfl(w0, e, 64);   // e >= cnt -> w from inactive lane = 0
        float a1 = __shfl(w1, e, 64);
        int dne = __shfl(dn, e, 64);
        int t1e = __shfl(tt.x, e, 64);
        int t2e = __shfl(tt.y, e, 64);
        const unsigned int* xr = xWp + (size_t)dne * 128 + 64;
        const unsigned int* rp = rW1p + (size_t)t1e * 64;
#pragma unroll
        for (int k = 0; k < 4; ++k) {
          int j2 = q + 16 * k;
          unsigned int ud = xr[j2];
          unsigned int ur = rp[j2];
          float rv0 = unpk_lo(ur), rv1 = unpk_hi(ur);
          if (t2e >= 0) {  // group-uniform branch
            unsigned int u2 = rW1p[(size_t)t2e * 64 + j2];
            rv0 += unpk_lo(u2);
            rv1 += unpk_hi(u2);
          }
          ac0[k] = fmaf(a0, unpk_lo(ud) + rv0, ac0[k]);
          ac1[k] = fmaf(a1, unpk_hi(ud) + rv1, ac1[k]);
        }
      }
    }
    // reduce across the 4 groups (lanes q, q+16, q+32, q+48)
#pragma unroll
    for (int k = 0; k < 4; ++k) {
      ac0[k] += __shfl_xor(ac0[k], 16, 64);
      ac0[k] += __shfl_xor(ac0[k], 32, 64);
      ac1[k] += __shfl_xor(ac1[k], 16, 64);
      ac1[k] += __shfl_xor(ac1[k], 32, 64);
    }
    float a0g = (g == 0) ? ac0[0] : (g == 1) ? ac0[1] : (g == 2) ? ac0[2] : ac0[3];
    float a1g = (g == 0) ? ac1[0] : (g == 1) ? ac1[1] : (g == 2) ? ac1[2] : ac1[3];
    float inv0 = 1.f / (d0 + SEPS), inv1 = 1.f / (d1 + SEPS);
    unsigned int us = xWp[(size_t)n * 128 + jj];
    float o0 = (a0g + d0 * unpk_lo(us)) * inv0;
    float o1 = (a1g + d1 * unpk_hi(us)) * inv1;
    r0 = (o0 > 0.f) ? o0 : __expf(o0) - 1.f;  // elu (concat=True)
    r1 = (o1 > 0.f) ? o1 : __expf(o1) - 1.f;
  }
  x1b[(size_t)n * 128 + jj] = f2bf(r0);
  x1b[(size_t)n * 128 + 64 + jj] = f2bf(r1);
}

// ---------------- layer-2 aggregation: same structure, fp32 out ----------------
__global__ __launch_bounds__(256) void k_agg2(
    const int* __restrict__ rowstart, const float* __restrict__ lgp2,
    const int* __restrict__ dnp, const int2* __restrict__ t12,
    const unsigned int* __restrict__ xWp, const unsigned int* __restrict__ rW2p,
    float* __restrict__ outp) {
  int n = blockIdx.x * 4 + (threadIdx.x >> 6);
  int lane = threadIdx.x & 63;
  int q = lane & 15, g = lane >> 4;
  int s0 = rowstart[n];
  int deg = rowstart[n + 1] - s0;
  int jj = q + 16 * g;
  float r0 = 0.f, r1 = 0.f;
  if (deg > 0) {
    float m = -3.4e38f, d = 0.f;
    float ac0[4] = {0.f, 0.f, 0.f, 0.f}, ac1[4] = {0.f, 0.f, 0.f, 0.f};
    for (int base = 0; base < deg; base += 64) {
      int i = base + lane;
      float lg = -3.4e38f;
      int dn = 0;
      int2 tt = make_int2(0, -1);
      if (i < deg) {
        lg = lgp2[s0 + i];
        dn = dnp[s0 + i];
        tt = t12[s0 + i];
      }
      float nm = fmaxf(m, wave_max64(lg));
      float rs = __expf(m - nm);
      float w = __expf(lg - nm);
      d = d * rs + wave_sum64(w);
#pragma unroll
      for (int k = 0; k < 4; ++k) {
        ac0[k] *= rs;
        ac1[k] *= rs;
      }
      m = nm;
      int cnt = min(64, deg - base);
      int steps = (cnt + 3) >> 2;
      for (int s = 0; s < steps; ++s) {
        int e = s * 4 + g;
        float a = __shfl(w, e, 64);
        int dne = __shfl(dn, e, 64);
        int t1e = __shfl(tt.x, e, 64);
        int t2e = __shfl(tt.y, e, 64);
        const unsigned int* xr = xWp + (size_t)dne * 128 + 64;
        const unsigned int* rp = rW2p + (size_t)t1e * 64;
#pragma unroll
        for (int k = 0; k < 4; ++k) {
          int j2 = q + 16 * k;
          unsigned int ud = xr[j2];
          unsigned int ur = rp[j2];
          float rv0 = unpk_lo(ur), rv1 = unpk_hi(ur);
          if (t2e >= 0) {
            unsigned int u2 = rW2p[(size_t)t2e * 64 + j2];
            rv0 += unpk_lo(u2);
            rv1 += unpk_hi(u2);
          }
          ac0[k] = fmaf(a, unpk_lo(ud) + rv0, ac0[k]);
          ac1[k] = fmaf(a, unpk_hi(ud) + rv1, ac1[k]);
        }
      }
    }
#pragma unroll
    for (int k = 0; k < 4; ++k) {
      ac0[k] += __shfl_xor(ac0[k], 16, 64);
      ac0[k] += __shfl_xor(ac0[k], 32, 64);
      ac1[k] += __shfl_xor(ac1[k], 16, 64);
      ac1[k] += __shfl_xor(ac1[k], 32, 64);
    }
    float a0g = (g == 0) ? ac0[0] : (g == 1) ? ac0[1] : (g == 2) ? ac0[2] : ac0[3];
    float a1g = (g == 0) ? ac1[0] : (g == 1) ? ac1[1] : (g == 2) ? ac1[2] : ac1[3];
    float inv = 1.f / (d + SEPS);
    unsigned int us = xWp[(size_t)n * 128 + jj];
    float o0 = (a0g + d * unpk_lo(us)) * inv;
    float o1 = (a1g + d * unpk_hi(us)) * inv;
    r0 = (o0 > 0.f) ? o0 : __expf(o0) - 1.f;  // final elu
    r1 = (o1 > 0.f) ? o1 : __expf(o1) - 1.f;
  }
  outp[(size_t)n * 128 + jj] = r0;
  outp[(size_t)n * 128 + 64 + jj] = r1;
}

// ---------------- launch ----------------
extern "C" void kernel_launch(void* const* d_in, const int* in_sizes, int n_in, void* d_out,
                              int out_size, void* d_ws, size_t ws_size, hipStream_t stream) {
  const int* edge_index = (const int*)d_in[0];
  const int* srcA = edge_index;
  const int* dstA = edge_index + ETOT;
  const float* x = (const float*)d_in[1];
  const float* r = (const float*)d_in[2];
  const int* et = (const int*)d_in[3];
  const int* et2 = (const int*)d_in[4];
  const float* Wh = (const float*)d_in[5];
  const float* ah = (const float*)d_in[6];
  const float* Wo = (const float*)d_in[7];
  const float* ao = (const float*)d_in[8];
  const float* Wr = (const float*)d_in[9];
  float* out = (float*)d_out;
  float* r2out = out + (size_t)NNODES * 128;

  // workspace layout (256-B aligned chunks)
  char* ws = (char*)d_ws;
  size_t o = 0;
  auto alloc = [&](size_t bytes) {
    char* p = ws + o;
    o += (bytes + 255) & ~(size_t)255;
    return p;
  };
  unsigned int* xWp = (unsigned int*)alloc((size_t)NNODES * 128 * 4);  // bf16-pair xW
  float* sc1 = (float*)alloc((size_t)NNODES * 4 * 4);  // NOTE: sc2 contiguous after sc1
  float* sc2 = (float*)alloc((size_t)NNODES * 2 * 4);
  unsigned int* rW1p = (unsigned int*)alloc((size_t)NREL * 64 * 4);
  float* srel1 = (float*)alloc(2 * NREL * 4);
  unsigned int* rW2p = (unsigned int*)alloc((size_t)NREL * 64 * 4);
  float* srel2 = (float*)alloc(NREL * 4);
  unsigned short* x1b = (unsigned short*)alloc((size_t)NNODES * 128 * 2);  // bf16 x1
  unsigned short* Wb1 = (unsigned short*)alloc(256 * 128 * 2);
  unsigned short* Wb2 = (unsigned short*)alloc(256 * 128 * 2);
  int* cnt = (int*)alloc(NNODES * 4);
  int* rowstart = (int*)alloc((NNODES + 1) * 4);
  int* cursor = (int*)alloc(NNODES * 4);
  int* blockTot = (int*)alloc(512 * 4);
  int* blockOff = (int*)alloc(512 * 4);
  int* perm = (int*)alloc(ETOT * 4);
  int* srcp = (int*)alloc(ETOT * 4);
  int* dnp = (int*)alloc(ETOT * 4);
  int2* t12 = (int2*)alloc((size_t)ETOT * 8);
  float2* lgp1 = (float2*)alloc((size_t)ETOT * 8);
  float* lgp2 = (float*)alloc(ETOT * 4);

  const int EB = (ETOT + 255) / 256;  // 1250

  // --- zero: cnt + sc1+sc2 (atomically accumulated by the GEMM epilogue) ---
  k_zero_int<<<(NNODES + 255) / 256, 256, 0, stream>>>(cnt, NNODES);
  k_zero_int<<<(NNODES * 6 + 255) / 256, 256, 0, stream>>>((int*)sc1, NNODES * 6);

  // --- CSR build ---
  k_count<<<EB, 256, 0, stream>>>(srcA, cnt);
  k_scan_a<<<NB_SCAN, 256, 0, stream>>>(cnt, rowstart, blockTot);
  k_scan_b<<<1, 512, 0, stream>>>(blockTot, blockOff);
  k_scan_c<<<NB_SCAN, 256, 0, stream>>>(rowstart, blockOff, cursor);
  k_scatter<<<EB, 256, 0, stream>>>(srcA, cursor, perm);

  // --- relation precompute + weight staging ---
  k_relprep1<<<NREL, 128, 0, stream>>>(r, Wh, ah, rW1p, srel1);
  k_r2<<<NREL, 128, 0, stream>>>(r, Wr, r2out);
  k_relprep2<<<NREL, 128, 0, stream>>>(r2out, Wo, ao, rW2p, srel2);
  k_packb<1><<<256, 128, 0, stream>>>(Wh, Wb1);
  k_packb<2><<<256, 128, 0, stream>>>(Wo, Wb2);

  // --- layer 1 ---
  k_gemm_mfma<1><<<GGRID, 256, 0, stream>>>(x, Wb1, ah, xWp, sc1);
  k_eprep1<<<EB, 256, 0, stream>>>(perm, srcA, dstA, et, et2, sc1, srel1, srcp, dnp, t12,
                                   lgp1);
  k_agg1<<<NNODES / 4, 256, 0, stream>>>(rowstart, lgp1, dnp, t12, xWp, rW1p, x1b);

  // --- layer 2 ---
  k_gemm_mfma<2><<<GGRID, 256, 0, stream>>>(x1b, Wb2, ao, xWp, sc2);
  k_eprep2<<<EB, 256, 0, stream>>>(srcp, dnp, t12, sc2, srel2, lgp2);
  k_agg2<<<NNODES / 4, 256, 0, stream>>>(rowstart, lgp2, dnp, t12, xWp, rW2p, out);
}

// Round 9
// 402.874 us; speedup vs baseline: 1.2130x; 1.2130x over previous
//
#include <hip/hip_runtime.h>
#include <math.h>

// Problem constants (from reference)
#define NNODES 100000
#define NREL 500
#define E1 288000
#define ETOT 320000
#define LALPHA 0.2f
#define SEPS 1e-16f
#define NB_SCAN ((NNODES + 255) / 256)  // 391 blocks of 256 for the scan
#define GTILES 6250                      // 100000 / 16 row-tiles, exact
#define GTPB 5                           // tiles per block
#define GGRID (GTILES / GTPB)            // 1250 blocks, exact

typedef __attribute__((ext_vector_type(8))) short bf16x8;
typedef __attribute__((ext_vector_type(4))) float f32x4;

// fp32 -> bf16 (round-to-nearest-even), header-independent
__device__ __forceinline__ unsigned short f2bf(float x) {
  unsigned int u = __float_as_uint(x);
  unsigned int r = (u + 0x7fffu + ((u >> 16) & 1u)) >> 16;
  return (unsigned short)r;
}
// pack two fp32 as bf16 pair (lo, hi) in one uint
__device__ __forceinline__ unsigned int packbf2(float lo, float hi) {
  return (unsigned int)f2bf(lo) | ((unsigned int)f2bf(hi) << 16);
}
__device__ __forceinline__ float unpk_lo(unsigned int u) { return __uint_as_float(u << 16); }
__device__ __forceinline__ float unpk_hi(unsigned int u) {
  return __uint_as_float(u & 0xffff0000u);
}
__device__ __forceinline__ float lrelu(float e) { return (e >= 0.f) ? e : LALPHA * e; }

// ---------------- wave (64-lane) reductions ----------------
__device__ __forceinline__ float wave_max64(float v) {
#pragma unroll
  for (int o = 32; o >= 1; o >>= 1) v = fmaxf(v, __shfl_xor(v, o, 64));
  return v;
}
__device__ __forceinline__ float wave_sum64(float v) {
#pragma unroll
  for (int o = 32; o >= 1; o >>= 1) v += __shfl_xor(v, o, 64);
  return v;
}
// reduce across the 16 lanes of a colv-group (bits 0..3)
__device__ __forceinline__ float red16(float v) {
  v += __shfl_xor(v, 1, 64);
  v += __shfl_xor(v, 2, 64);
  v += __shfl_xor(v, 4, 64);
  v += __shfl_xor(v, 8, 64);
  return v;
}

// ---------------- CSR build ----------------
__global__ void k_zero_int(int* __restrict__ p, int n) {
  int i = blockIdx.x * blockDim.x + threadIdx.x;
  if (i < n) p[i] = 0;
}

__global__ void k_count(const int* __restrict__ src, int* __restrict__ cnt) {
  int e = blockIdx.x * blockDim.x + threadIdx.x;
  if (e < ETOT) atomicAdd(&cnt[src[e]], 1);
}

__global__ void k_scan_a(const int* __restrict__ cnt, int* __restrict__ rowstart,
                         int* __restrict__ blockTot) {
  __shared__ int s[256];
  int t = threadIdx.x;
  int idx = blockIdx.x * 256 + t;
  int v = (idx < NNODES) ? cnt[idx] : 0;
  s[t] = v;
  __syncthreads();
  for (int off = 1; off < 256; off <<= 1) {
    int xv = (t >= off) ? s[t - off] : 0;
    __syncthreads();
    s[t] += xv;
    __syncthreads();
  }
  if (idx < NNODES) rowstart[idx] = s[t] - v;  // exclusive within block
  if (t == 255) blockTot[blockIdx.x] = s[255];
}

__global__ void k_scan_b(const int* __restrict__ blockTot, int* __restrict__ blockOff) {
  __shared__ int s[512];
  int t = threadIdx.x;
  int v = (t < NB_SCAN) ? blockTot[t] : 0;
  s[t] = v;
  __syncthreads();
  for (int off = 1; off < 512; off <<= 1) {
    int xv = (t >= off) ? s[t - off] : 0;
    __syncthreads();
    s[t] += xv;
    __syncthreads();
  }
  if (t < NB_SCAN) blockOff[t] = s[t] - v;  // exclusive
}

__global__ void k_scan_c(int* __restrict__ rowstart, const int* __restrict__ blockOff,
                         int* __restrict__ cursor) {
  int idx = blockIdx.x * 256 + threadIdx.x;
  if (idx < NNODES) {
    int v = rowstart[idx] + blockOff[blockIdx.x];
    rowstart[idx] = v;
    cursor[idx] = v;
  }
  if (idx == 0) rowstart[NNODES] = ETOT;
}

__global__ void k_scatter(const int* __restrict__ src, int* __restrict__ cursor,
                          int* __restrict__ perm) {
  int e = blockIdx.x * blockDim.x + threadIdx.x;
  if (e < ETOT) {
    int pos = atomicAdd(&cursor[src[e]], 1);
    perm[pos] = e;
  }
}

// ---------------- relation-level precompute ----------------
// rW1p[t][j] = bf16pair(rel[2j], rel[2j+1]), rel = concat(h0 64, h1 64)  (plain layout)
__global__ void k_relprep1(const float* __restrict__ r, const float* __restrict__ Wh,
                           const float* __restrict__ ah, unsigned int* __restrict__ rW1p,
                           float* __restrict__ srel1) {
  __shared__ float vals[128];
  int t = blockIdx.x;    // 0..499
  int tid = threadIdx.x; // 0..127: h = tid>>6, kk = tid&63
  int h = tid >> 6, kk = tid & 63;
  const float* wcol = Wh + h * 24576 + 256 * 64 + kk;
  const float* rrow = r + t * 128;
  float acc = 0.f;
#pragma unroll 4
  for (int d = 0; d < 128; ++d) acc = fmaf(rrow[d], wcol[d * 64], acc);
  vals[tid] = acc;
  float p = wave_sum64(acc * ah[h * 64 + kk]);
  if (kk == 0) srel1[t * 2 + h] = p;
  __syncthreads();
  if (tid < 64) rW1p[t * 64 + tid] = packbf2(vals[2 * tid], vals[2 * tid + 1]);
}

// r2[t][c] = sum_d r[t][d] * W_r[d][c]   (also one of the two outputs)
__global__ void k_r2(const float* __restrict__ r, const float* __restrict__ Wr,
                     float* __restrict__ r2out) {
  int t = blockIdx.x;   // 0..499
  int c = threadIdx.x;  // 0..127
  float acc = 0.f;
#pragma unroll 4
  for (int d = 0; d < 128; ++d) acc = fmaf(r[t * 128 + d], Wr[d * 128 + c], acc);
  r2out[t * 128 + c] = acc;
}

// rW2p[t][j] = bf16pair(rW2[t][2j], rW2[t][2j+1]); srel2[t] = rW2[t] . a_out
__global__ void k_relprep2(const float* __restrict__ r2, const float* __restrict__ Wo,
                           const float* __restrict__ ao, unsigned int* __restrict__ rW2p,
                           float* __restrict__ srel2) {
  __shared__ float s[128];
  __shared__ float vals[128];
  int t = blockIdx.x;   // 0..499
  int k = threadIdx.x;  // 0..127
  float acc = 0.f;
#pragma unroll 4
  for (int d = 0; d < 128; ++d) acc = fmaf(r2[t * 128 + d], Wo[(256 + d) * 128 + k], acc);
  vals[k] = acc;
  s[k] = acc * ao[k];
  __syncthreads();
  for (int off = 64; off >= 1; off >>= 1) {
    if (k < off) s[k] += s[k + off];
    __syncthreads();
  }
  if (k == 0) srel2[t] = s[0];
  if (k < 64) rW2p[t * 64 + k] = packbf2(vals[2 * k], vals[2 * k + 1]);
}

// ---------------- MFMA weight packing: Wb[c][d] bf16, B^T layout ----------------
// col order: LAYER1 c = part*128 + h*64 + kc; LAYER2 c = part*128 + kc
template <int LAYER>
__global__ void k_packb(const float* __restrict__ W, unsigned short* __restrict__ Wb) {
  int c = blockIdx.x;   // 0..255
  int d = threadIdx.x;  // 0..127
  float v;
  if (LAYER == 1) {
    int h = (c >> 6) & 1, part = c >> 7, kc = c & 63;
    v = W[h * 24576 + (part * 128 + d) * 64 + kc];
  } else {
    int part = c >> 7, kc = c & 127;
    v = W[(part * 128 + d) * 128 + kc];
  }
  Wb[c * 128 + d] = f2bf(v);
}

// ---------------- MFMA GEMM: xWp[N][128 uints] (plain bf16 row) = X @ Wb^T ----------------
// Wave owns 64 CONTIGUOUS cols [64*wave, 64*wave+64): B = 16 b128 resident (64 VGPR).
// No LDS, no barriers, no atomics. A double-buffered in registers across GTPB row-tiles.
// Per row, wave writes one aligned 128-B chunk (full L2 line -> no write amplification).
// sc: wave w covers exactly one slot; direct store.
//   LAYER1 slot = ((w&1)<<1)|(w>>1)  -> sc1[n][4] = {ss_h0, sd_h0, ss_h1, sd_h1}
//   LAYER2 slot = w                  -> sc2[n][4], eprep2 sums pairs.
template <int LAYER>
__global__ __launch_bounds__(256) void k_gemm_mfma(const void* __restrict__ Xin,
                                                   const unsigned short* __restrict__ Wb,
                                                   const float* __restrict__ avec,
                                                   unsigned int* __restrict__ xWp,
                                                   float* __restrict__ sc) {
  const int lane = threadIdx.x & 63;
  const int wave = threadIdx.x >> 6;
  const int colv = lane & 15;
  const int kg = lane >> 4;

  // ---- B fragments: 16 x b128, loaded once (Wb 64 KB, L2/L3-resident) ----
  bf16x8 b[4][4];
#pragma unroll
  for (int t = 0; t < 4; ++t)
#pragma unroll
    for (int s = 0; s < 4; ++s)
      b[t][s] = *(const bf16x8*)(Wb + (size_t)(wave * 64 + t * 16 + colv) * 128 + s * 32 +
                                 kg * 8);
  float av[4];
#pragma unroll
  for (int t = 0; t < 4; ++t) av[t] = avec[(wave & 1) * 64 + t * 16 + colv];
  const int slot = (LAYER == 1) ? (((wave & 1) << 1) | (wave >> 1)) : wave;

  const float4* xf4 = (const float4*)Xin;
  const uint4* xu4 = (const uint4*)Xin;
  int tile = blockIdx.x * GTPB;

  float4 cf[8];
  uint4 cu[4];
  // prologue: load tile 0 (row = tile*16 + colv)
  {
    int ar = tile * 16 + colv;
    if (LAYER == 1) {
      int base = ar * 32 + kg * 2;
#pragma unroll
      for (int s = 0; s < 4; ++s) {
        cf[2 * s] = xf4[base + s * 8];
        cf[2 * s + 1] = xf4[base + s * 8 + 1];
      }
    } else {
      int base = ar * 16 + kg;
#pragma unroll
      for (int s = 0; s < 4; ++s) cu[s] = xu4[base + s * 4];
    }
  }

  for (int it = 0; it < GTPB; ++it, ++tile) {
    // ---- issue next tile's loads (hide latency under MFMA+stores) ----
    float4 nf[8];
    uint4 nu[4];
    const bool hasnext = (it + 1 < GTPB);
    if (hasnext) {
      int ar = (tile + 1) * 16 + colv;
      if (LAYER == 1) {
        int base = ar * 32 + kg * 2;
#pragma unroll
        for (int s = 0; s < 4; ++s) {
          nf[2 * s] = xf4[base + s * 8];
          nf[2 * s + 1] = xf4[base + s * 8 + 1];
        }
      } else {
        int base = ar * 16 + kg;
#pragma unroll
        for (int s = 0; s < 4; ++s) nu[s] = xu4[base + s * 4];
      }
    }

    // ---- build A fragments ----
    bf16x8 a[4];
    if (LAYER == 1) {
#pragma unroll
      for (int s = 0; s < 4; ++s) {
        union {
          unsigned short us[8];
          bf16x8 v;
        } u;
        u.us[0] = f2bf(cf[2 * s].x); u.us[1] = f2bf(cf[2 * s].y);
        u.us[2] = f2bf(cf[2 * s].z); u.us[3] = f2bf(cf[2 * s].w);
        u.us[4] = f2bf(cf[2 * s + 1].x); u.us[5] = f2bf(cf[2 * s + 1].y);
        u.us[6] = f2bf(cf[2 * s + 1].z); u.us[7] = f2bf(cf[2 * s + 1].w);
        a[s] = u.v;
      }
    } else {
#pragma unroll
      for (int s = 0; s < 4; ++s) {
        union {
          uint4 q;
          bf16x8 v;
        } u;
        u.q = cu[s];
        a[s] = u.v;
      }
    }

    // ---- MFMA: 4 col-tiles x 4 K-steps ----
    f32x4 acc[4];
#pragma unroll
    for (int t = 0; t < 4; ++t) acc[t] = (f32x4){0.f, 0.f, 0.f, 0.f};
#pragma unroll
    for (int s = 0; s < 4; ++s)
#pragma unroll
      for (int t = 0; t < 4; ++t)
        acc[t] = __builtin_amdgcn_mfma_f32_16x16x32_bf16(a[s], b[t][s], acc[t], 0, 0, 0);

    // ---- stores: adjacent-pair pack via shfl, even lanes store (128 B/row/wave) ----
    const int rbase = tile * 16 + kg * 4;
    const int m = colv >> 1;
    const bool evn = (colv & 1) == 0;
#pragma unroll
    for (int i = 0; i < 4; ++i) {
      unsigned int* orow = xWp + (size_t)(rbase + i) * 128 + wave * 32;
#pragma unroll
      for (int t = 0; t < 4; ++t) {
        float lo = acc[t][i];
        float other = __shfl_xor(lo, 1, 64);
        if (evn) orow[t * 8 + m] = packbf2(lo, other);
      }
      // sc epilogue: this wave's slot for this row
      float p = 0.f;
#pragma unroll
      for (int t = 0; t < 4; ++t) p = fmaf(acc[t][i], av[t], p);
      p = red16(p);
      if (colv == 0) sc[(size_t)(rbase + i) * 4 + slot] = p;
    }

    // ---- rotate buffers ----
    if (hasnext) {
      if (LAYER == 1) {
#pragma unroll
        for (int j = 0; j < 8; ++j) cf[j] = nf[j];
      } else {
#pragma unroll
        for (int j = 0; j < 4; ++j) cu[j] = nu[j];
      }
    }
  }
}

// ---------------- edge-parallel logit precompute ----------------
__global__ void k_eprep1(const int* __restrict__ perm, const int* __restrict__ srcA,
                         const int* __restrict__ dstA, const int* __restrict__ et,
                         const int* __restrict__ et2, const float* __restrict__ sc1,
                         const float* __restrict__ srel1, int* __restrict__ srcp,
                         int* __restrict__ dnp, int2* __restrict__ t12,
                         float2* __restrict__ lgp1) {
  int p = blockIdx.x * 256 + threadIdx.x;
  if (p >= ETOT) return;
  int ed = perm[p];
  int src = srcA[ed], dn = dstA[ed];
  int t1, t2 = -1;
  float rel0, rel1;
  if (ed < E1) {
    t1 = et[ed];
    float2 sr = ((const float2*)srel1)[t1];
    rel0 = sr.x;
    rel1 = sr.y;
  } else {
    int2 tt = ((const int2*)et2)[ed - E1];
    t1 = tt.x;
    t2 = tt.y;
    float2 sa = ((const float2*)srel1)[t1];
    float2 sb = ((const float2*)srel1)[t2];
    rel0 = sa.x + sb.x;
    rel1 = sa.y + sb.y;
  }
  // sc1[n] = {ss_h0, sd_h0, ss_h1, sd_h1}
  float4 ssv = ((const float4*)sc1)[src];
  float4 sdv = ((const float4*)sc1)[dn];
  lgp1[p] = make_float2(lrelu(ssv.x + sdv.y + rel0), lrelu(ssv.z + sdv.w + rel1));
  srcp[p] = src;
  dnp[p] = dn;
  t12[p] = make_int2(t1, t2);
}

// sc2[n] = {p0a, p0b, p1a, p1b}: ss = p0a+p0b, sd = p1a+p1b
__global__ void k_eprep2(const int* __restrict__ srcp, const int* __restrict__ dnp,
                         const int2* __restrict__ t12, const float* __restrict__ sc2,
                         const float* __restrict__ srel2, float* __restrict__ lgp2) {
  int p = blockIdx.x * 256 + threadIdx.x;
  if (p >= ETOT) return;
  int src = srcp[p], dn = dnp[p];
  int2 tt = t12[p];
  float rel = srel2[tt.x];
  if (tt.y >= 0) rel += srel2[tt.y];
  float4 ssv = ((const float4*)sc2)[src];
  float4 sdv = ((const float4*)sc2)[dn];
  lgp2[p] = lrelu((ssv.x + ssv.y) + (sdv.z + sdv.w) + rel);
}

// ---------------- layer-1 aggregation: wave/node, 4-edge-parallel groups ----------------
// Plain layout: uint j of a row = cols (2j, 2j+1). k<2 -> head0 cols, k>=2 -> head1.
__global__ __launch_bounds__(256) void k_agg1(
    const int* __restrict__ rowstart, const float2* __restrict__ lgp1,
    const int* __restrict__ dnp, const int2* __restrict__ t12,
    const unsigned int* __restrict__ xWp, const unsigned int* __restrict__ rW1p,
    unsigned int* __restrict__ x1b) {
  int n = blockIdx.x * 4 + (threadIdx.x >> 6);
  int lane = threadIdx.x & 63;
  int q = lane & 15, g = lane >> 4;
  int s0 = rowstart[n];
  int deg = rowstart[n + 1] - s0;
  int jj = q + 16 * g;
  float r0 = 0.f, r1 = 0.f;
  if (deg > 0) {
    float m0 = -3.4e38f, m1 = -3.4e38f, d0 = 0.f, d1 = 0.f;
    float ac0[4] = {0.f, 0.f, 0.f, 0.f}, ac1[4] = {0.f, 0.f, 0.f, 0.f};
    for (int base = 0; base < deg; base += 64) {
      int i = base + lane;
      float lg0 = -3.4e38f, lg1 = -3.4e38f;
      int dn = 0;
      int2 tt = make_int2(0, -1);
      if (i < deg) {
        float2 l2 = lgp1[s0 + i];
        lg0 = l2.x;
        lg1 = l2.y;
        dn = dnp[s0 + i];
        tt = t12[s0 + i];
      }
      float nm0 = fmaxf(m0, wave_max64(lg0));
      float nm1 = fmaxf(m1, wave_max64(lg1));
      float rs0 = __expf(m0 - nm0), rs1 = __expf(m1 - nm1);
      float w0 = __expf(lg0 - nm0), w1 = __expf(lg1 - nm1);  // invalid lanes -> 0
      d0 = d0 * rs0 + wave_sum64(w0);
      d1 = d1 * rs1 + wave_sum64(w1);
#pragma unroll
      for (int k = 0; k < 4; ++k) {
        float rs = (k < 2) ? rs0 : rs1;
        ac0[k] *= rs;
        ac1[k] *= rs;
      }
      m0 = nm0;
      m1 = nm1;
      int cnt = min(64, deg - base);
      int steps = (cnt + 3) >> 2;
      for (int s = 0; s < steps; ++s) {
        int e = s * 4 + g;  // this group's edge within the chunk (<=63)
        float a0 = __shfl(w0, e, 64);   // e >= cnt -> w from inactive lane = 0
        float a1 = __shfl(w1, e, 64);
        int dne = __shfl(dn, e, 64);
        int t1e = __shfl(tt.x, e, 64);
        int t2e = __shfl(tt.y, e, 64);
        const unsigned int* xr = xWp + (size_t)dne * 128 + 64;
        const unsigned int* rp = rW1p + (size_t)t1e * 64;
#pragma unroll
        for (int k = 0; k < 4; ++k) {
          int j2 = q + 16 * k;
          float as = (k < 2) ? a0 : a1;  // head by col range (compile-time per k)
          unsigned int ud = xr[j2];
          unsigned int ur = rp[j2];
          float rv0 = unpk_lo(ur), rv1 = unpk_hi(ur);
          if (t2e >= 0) {  // group-uniform branch
            unsigned int u2 = rW1p[(size_t)t2e * 64 + j2];
            rv0 += unpk_lo(u2);
            rv1 += unpk_hi(u2);
          }
          ac0[k] = fmaf(as, unpk_lo(ud) + rv0, ac0[k]);
          ac1[k] = fmaf(as, unpk_hi(ud) + rv1, ac1[k]);
        }
      }
    }
    // reduce across the 4 groups (lanes q, q+16, q+32, q+48)
#pragma unroll
    for (int k = 0; k < 4; ++k) {
      ac0[k] += __shfl_xor(ac0[k], 16, 64);
      ac0[k] += __shfl_xor(ac0[k], 32, 64);
      ac1[k] += __shfl_xor(ac1[k], 16, 64);
      ac1[k] += __shfl_xor(ac1[k], 32, 64);
    }
    float a0g = (g == 0) ? ac0[0] : (g == 1) ? ac0[1] : (g == 2) ? ac0[2] : ac0[3];
    float a1g = (g == 0) ? ac1[0] : (g == 1) ? ac1[1] : (g == 2) ? ac1[2] : ac1[3];
    float dsel = (g < 2) ? d0 : d1;
    float isel = 1.f / (dsel + SEPS);
    unsigned int us = xWp[(size_t)n * 128 + jj];
    float o0 = (a0g + dsel * unpk_lo(us)) * isel;
    float o1 = (a1g + dsel * unpk_hi(us)) * isel;
    r0 = (o0 > 0.f) ? o0 : __expf(o0) - 1.f;  // elu (concat=True)
    r1 = (o1 > 0.f) ? o1 : __expf(o1) - 1.f;
  }
  x1b[(size_t)n * 64 + jj] = packbf2(r0, r1);  // plain bf16 row (cols 2jj, 2jj+1)
}

// ---------------- layer-2 aggregation: same structure, fp32 out ----------------
__global__ __launch_bounds__(256) void k_agg2(
    const int* __restrict__ rowstart, const float* __restrict__ lgp2,
    const int* __restrict__ dnp, const int2* __restrict__ t12,
    const unsigned int* __restrict__ xWp, const unsigned int* __restrict__ rW2p,
    float* __restrict__ outp) {
  int n = blockIdx.x * 4 + (threadIdx.x >> 6);
  int lane = threadIdx.x & 63;
  int q = lane & 15, g = lane >> 4;
  int s0 = rowstart[n];
  int deg = rowstart[n + 1] - s0;
  int jj = q + 16 * g;
  float r0 = 0.f, r1 = 0.f;
  if (deg > 0) {
    float m = -3.4e38f, d = 0.f;
    float ac0[4] = {0.f, 0.f, 0.f, 0.f}, ac1[4] = {0.f, 0.f, 0.f, 0.f};
    for (int base = 0; base < deg; base += 64) {
      int i = base + lane;
      float lg = -3.4e38f;
      int dn = 0;
      int2 tt = make_int2(0, -1);
      if (i < deg) {
        lg = lgp2[s0 + i];
        dn = dnp[s0 + i];
        tt = t12[s0 + i];
      }
      float nm = fmaxf(m, wave_max64(lg));
      float rs = __expf(m - nm);
      float w = __expf(lg - nm);
      d = d * rs + wave_sum64(w);
#pragma unroll
      for (int k = 0; k < 4; ++k) {
        ac0[k] *= rs;
        ac1[k] *= rs;
      }
      m = nm;
      int cnt = min(64, deg - base);
      int steps = (cnt + 3) >> 2;
      for (int s = 0; s < steps; ++s) {
        int e = s * 4 + g;
        float a = __shfl(w, e, 64);
        int dne = __shfl(dn, e, 64);
        int t1e = __shfl(tt.x, e, 64);
        int t2e = __shfl(tt.y, e, 64);
        const unsigned int* xr = xWp + (size_t)dne * 128 + 64;
        const unsigned int* rp = rW2p + (size_t)t1e * 64;
#pragma unroll
        for (int k = 0; k < 4; ++k) {
          int j2 = q + 16 * k;
          unsigned int ud = xr[j2];
          unsigned int ur = rp[j2];
          float rv0 = unpk_lo(ur), rv1 = unpk_hi(ur);
          if (t2e >= 0) {
            unsigned int u2 = rW2p[(size_t)t2e * 64 + j2];
            rv0 += unpk_lo(u2);
            rv1 += unpk_hi(u2);
          }
          ac0[k] = fmaf(a, unpk_lo(ud) + rv0, ac0[k]);
          ac1[k] = fmaf(a, unpk_hi(ud) + rv1, ac1[k]);
        }
      }
    }
#pragma unroll
    for (int k = 0; k < 4; ++k) {
      ac0[k] += __shfl_xor(ac0[k], 16, 64);
      ac0[k] += __shfl_xor(ac0[k], 32, 64);
      ac1[k] += __shfl_xor(ac1[k], 16, 64);
      ac1[k] += __shfl_xor(ac1[k], 32, 64);
    }
    float a0g = (g == 0) ? ac0[0] : (g == 1) ? ac0[1] : (g == 2) ? ac0[2] : ac0[3];
    float a1g = (g == 0) ? ac1[0] : (g == 1) ? ac1[1] : (g == 2) ? ac1[2] : ac1[3];
    float inv = 1.f / (d + SEPS);
    unsigned int us = xWp[(size_t)n * 128 + jj];
    float o0 = (a0g + d * unpk_lo(us)) * inv;
    float o1 = (a1g + d * unpk_hi(us)) * inv;
    r0 = (o0 > 0.f) ? o0 : __expf(o0) - 1.f;  // final elu
    r1 = (o1 > 0.f) ? o1 : __expf(o1) - 1.f;
  }
  ((float2*)outp)[(size_t)n * 64 + jj] = make_float2(r0, r1);  // cols 2jj, 2jj+1
}

// ---------------- launch ----------------
extern "C" void kernel_launch(void* const* d_in, const int* in_sizes, int n_in, void* d_out,
                              int out_size, void* d_ws, size_t ws_size, hipStream_t stream) {
  const int* edge_index = (const int*)d_in[0];
  const int* srcA = edge_index;
  const int* dstA = edge_index + ETOT;
  const float* x = (const float*)d_in[1];
  const float* r = (const float*)d_in[2];
  const int* et = (const int*)d_in[3];
  const int* et2 = (const int*)d_in[4];
  const float* Wh = (const float*)d_in[5];
  const float* ah = (const float*)d_in[6];
  const float* Wo = (const float*)d_in[7];
  const float* ao = (const float*)d_in[8];
  const float* Wr = (const float*)d_in[9];
  float* out = (float*)d_out;
  float* r2out = out + (size_t)NNODES * 128;

  // workspace layout (256-B aligned chunks)
  char* ws = (char*)d_ws;
  size_t o = 0;
  auto alloc = [&](size_t bytes) {
    char* p = ws + o;
    o += (bytes + 255) & ~(size_t)255;
    return p;
  };
  unsigned int* xWp = (unsigned int*)alloc((size_t)NNODES * 128 * 4);  // plain bf16 rows
  float* sc1 = (float*)alloc((size_t)NNODES * 4 * 4);
  float* sc2 = (float*)alloc((size_t)NNODES * 4 * 4);  // 4 slots, summed in eprep2
  unsigned int* rW1p = (unsigned int*)alloc((size_t)NREL * 64 * 4);
  float* srel1 = (float*)alloc(2 * NREL * 4);
  unsigned int* rW2p = (unsigned int*)alloc((size_t)NREL * 64 * 4);
  float* srel2 = (float*)alloc(NREL * 4);
  unsigned int* x1b = (unsigned int*)alloc((size_t)NNODES * 64 * 4);  // plain bf16 x1
  unsigned short* Wb1 = (unsigned short*)alloc(256 * 128 * 2);
  unsigned short* Wb2 = (unsigned short*)alloc(256 * 128 * 2);
  int* cnt = (int*)alloc(NNODES * 4);
  int* rowstart = (int*)alloc((NNODES + 1) * 4);
  int* cursor = (int*)alloc(NNODES * 4);
  int* blockTot = (int*)alloc(512 * 4);
  int* blockOff = (int*)alloc(512 * 4);
  int* perm = (int*)alloc(ETOT * 4);
  int* srcp = (int*)alloc(ETOT * 4);
  int* dnp = (int*)alloc(ETOT * 4);
  int2* t12 = (int2*)alloc((size_t)ETOT * 8);
  float2* lgp1 = (float2*)alloc((size_t)ETOT * 8);
  float* lgp2 = (float*)alloc(ETOT * 4);

  const int EB = (ETOT + 255) / 256;  // 1250

  // --- CSR build ---
  k_zero_int<<<(NNODES + 255) / 256, 256, 0, stream>>>(cnt, NNODES);
  k_count<<<EB, 256, 0, stream>>>(srcA, cnt);
  k_scan_a<<<NB_SCAN, 256, 0, stream>>>(cnt, rowstart, blockTot);
  k_scan_b<<<1, 512, 0, stream>>>(blockTot, blockOff);
  k_scan_c<<<NB_SCAN, 256, 0, stream>>>(rowstart, blockOff, cursor);
  k_scatter<<<EB, 256, 0, stream>>>(srcA, cursor, perm);

  // --- relation precompute + weight staging ---
  k_relprep1<<<NREL, 128, 0, stream>>>(r, Wh, ah, rW1p, srel1);
  k_r2<<<NREL, 128, 0, stream>>>(r, Wr, r2out);
  k_relprep2<<<NREL, 128, 0, stream>>>(r2out, Wo, ao, rW2p, srel2);
  k_packb<1><<<256, 128, 0, stream>>>(Wh, Wb1);
  k_packb<2><<<256, 128, 0, stream>>>(Wo, Wb2);

  // --- layer 1 ---
  k_gemm_mfma<1><<<GGRID, 256, 0, stream>>>(x, Wb1, ah, xWp, sc1);
  k_eprep1<<<EB, 256, 0, stream>>>(perm, srcA, dstA, et, et2, sc1, srel1, srcp, dnp, t12,
                                   lgp1);
  k_agg1<<<NNODES / 4, 256, 0, stream>>>(rowstart, lgp1, dnp, t12, xWp, rW1p, x1b);

  // --- layer 2 ---
  k_gemm_mfma<2><<<GGRID, 256, 0, stream>>>(x1b, Wb2, ao, xWp, sc2);
  k_eprep2<<<EB, 256, 0, stream>>>(srcp, dnp, t12, sc2, srel2, lgp2);
  k_agg2<<<NNODES / 4, 256, 0, stream>>>(rowstart, lgp2, dnp, t12, xWp, rW2p, out);
}